// Round 3
// baseline (385.221 us; speedup 1.0000x reference)
//
#include <hip/hip_runtime.h>

typedef unsigned short u16;
typedef unsigned int u32;
typedef __attribute__((ext_vector_type(8))) short short8;
typedef __attribute__((ext_vector_type(4))) float floatx4;

static constexpr int M = 16384, N = 2048, K = 2048;

// ---- helpers -------------------------------------------------------------

__device__ inline u16 f32_to_bf16(float x) {
    u32 u = __float_as_uint(x);
    u += 0x7FFFu + ((u >> 16) & 1u);
    return (u16)(u >> 16);
}

// RNE round to e4m3 grid; valid for x in [2^-6, 448] (normal e4m3 range,
// guaranteed by the preceding clip). 3 mantissa bits -> round at fp32 bit 20.
__device__ inline float e4m3_rne(float x) {
    u32 u = __float_as_uint(x);
    u += 0x7FFFFu + ((u >> 20) & 1u);
    u &= 0xFFF00000u;
    return __uint_as_float(u);
}

// decode fp4 e2m1 code (4 bits incl. sign) -> float {0,.5,1,1.5,2,3,4,6}*sign
__device__ inline float fp4_dec(u32 c) {
    u32 e = (c >> 1) & 3u;
    float m = (float)(c & 1u);
    float v = e ? (2.0f + m) * (float)(1u << e) * 0.25f : 0.5f * m;
    return (c & 8u) ? -v : v;
}

// reference fp4_121_positive with jnp.round == RNE == rintf
__device__ inline float fp4_round_mag(float a) {
    if (a < 2.0f) return rintf(2.0f * a) * 0.5f;
    if (a < 4.0f) return rintf(a);
    return 2.0f * rintf(a * 0.5f);
}

__device__ inline float pts_from_amax(float amax) {
    // clip(amax / 448, 2^-6, 448); true IEEE division to match reference
    return fminf(fmaxf(amax / 448.0f, 0.015625f), 448.0f);
}

// ---- kernel 1a: partial amax + absorbed weight dequant ------------------
// The weight-dequant path is independent of amax, so it rides along here:
// its 24 MB of traffic overlaps the 134 MB amax stream instead of adding
// a serial phase to prep.

__global__ void amax_part(const float4* __restrict__ x, float* __restrict__ part, int n4,
                          const int* __restrict__ wp, const float* __restrict__ wsc,
                          const float* __restrict__ wgs, u16* __restrict__ wq) {
    int idx = blockIdx.x * blockDim.x + threadIdx.x;
    int stride = gridDim.x * blockDim.x;
    float m = 0.0f;
    for (int i = idx; i < n4; i += stride) {
        float4 v = x[i];
        m = fmaxf(m, fmaxf(fmaxf(fabsf(v.x), fabsf(v.y)), fmaxf(fabsf(v.z), fabsf(v.w))));
    }

    // weight dequant: N*K/2 = 2M bytes, 4 per thread (grid 2048x256)
    float ginv = wgs[0];
#pragma unroll
    for (int g = 0; g < 4; g++) {
        int i = idx + g * 524288;                  // coalesced
        int n = i >> 10;                           // Khalf = 1024
        int kb = i & 1023;
        u32 byte = (u32)wp[i] & 0xFFu;
        float scale = wsc[(size_t)n * (K / 16) + (kb >> 3)] / ginv;
        float lo = fp4_dec(byte & 0xFu) * scale;
        float hi = fp4_dec((byte >> 4) & 0xFu) * scale;
        ((u32*)wq)[i] = (u32)f32_to_bf16(lo) | ((u32)f32_to_bf16(hi) << 16);
    }

#pragma unroll
    for (int off = 32; off > 0; off >>= 1)
        m = fmaxf(m, __shfl_down(m, off));
    __shared__ float sm[4];
    if ((threadIdx.x & 63) == 0) sm[threadIdx.x >> 6] = m;
    __syncthreads();
    if (threadIdx.x == 0)
        part[blockIdx.x] = fmaxf(fmaxf(sm[0], sm[1]), fmaxf(sm[2], sm[3]));
}

// ---- kernel 1b: finalize amax (1 block, 1024 threads, 2048 partials) ----

__global__ void amax_fin(const float* __restrict__ part, u32* __restrict__ out) {
    int t = threadIdx.x;
    float m = fmaxf(part[t], part[t + 1024]);
#pragma unroll
    for (int off = 32; off > 0; off >>= 1)
        m = fmaxf(m, __shfl_down(m, off));
    __shared__ float sm[16];
    if ((t & 63) == 0) sm[t >> 6] = m;
    __syncthreads();
    if (t < 16) {
        m = sm[t];
#pragma unroll
        for (int off = 8; off > 0; off >>= 1)
            m = fmaxf(m, __shfl_down(m, off));
        if (t == 0) *out = __float_as_uint(m);
    }
}

// ---- kernel 2: QDQ x -> bf16 A = lp * sbs (exact in bf16) ---------------

static constexpr int QB = (M * K / 4) / 256;        // 32768 quant blocks

__global__ void prep(const float4* __restrict__ x, uint2* __restrict__ aq,
                     const u32* __restrict__ amax_bits) {
    int idx = blockIdx.x * blockDim.x + threadIdx.x;
    float4 v = x[idx];

    float bm = fmaxf(fmaxf(fabsf(v.x), fabsf(v.y)), fmaxf(fabsf(v.z), fabsf(v.w)));
    bm = fmaxf(bm, __shfl_xor(bm, 1));
    bm = fmaxf(bm, __shfl_xor(bm, 2));   // 4-lane group = one 16-block

    float pts = pts_from_amax(__uint_as_float(*amax_bits));
    float bs = bm / 6.0f;
    float sbs = e4m3_rne(fminf(fmaxf(bs / pts, 0.015625f), 448.0f));
    float ts = pts * sbs;

    float vf[4] = {v.x, v.y, v.z, v.w};
    u16 o[4];
#pragma unroll
    for (int i = 0; i < 4; i++) {
        float s = vf[i] / ts;                       // IEEE div, matches ref
        s = fminf(fmaxf(s, -6.0f), 6.0f);
        float lp = copysignf(fp4_round_mag(fabsf(s)), s);
        o[i] = f32_to_bf16(lp * sbs);               // exact product
    }
    aq[idx] = *(const uint2*)o;
}

// ---- kernel 3: bf16 GEMM, 256x256 tile, 6-phase counted-vmcnt schedule --
//
// m201-template port, phases P3+P4 and P7+P8 merged (they had no ds_reads):
// 32-MFMA setprio clusters, 12 barriers/iter instead of 16. Launched as TWO
// independent 256-block dispatches (bm halves) so prep/amax become visible
// in the rocprof top-5 (no perf cost: the dispatches have no mutual deps).
//
// Stage slot hazards (1 barrier-pair between any region's last reader-MFMA
// and the STG that overwrites it; reads are lgkm-drained by their MFMAs):
//   P1  stages Y.A0: last read P78 prev iter (RD_A(1,1))     -> safe
//   P2  stages Y.A1: last read P78 prev iter                  -> safe
//   P34 stages X.B0+X.B1: last reads P1 (Qb0) / P2 (Qb1)      -> safe
//   P5  stages X.A0: last read P34 (RD_A(0,1))                -> safe
//   P6  stages X.A1: last read P34                            -> safe
//   P78 stages Y.B0+Y.B1: last reads P5 (Qb0) / P6 (Qb1)      -> safe
// Checkpoints (12 glds outstanding, keep 4 newest):
//   P34 CHK4: confirms Y.A (P1/P2) + Y.B (prev P78) before P5 reads Y
//   P78 CHK4: confirms X.A (P5/P6) + X.B (P34) before next P1 reads X

#define GLDS(g, l)                                                              \
    __builtin_amdgcn_global_load_lds(                                           \
        (const __attribute__((address_space(1))) unsigned int*)(g),             \
        (__attribute__((address_space(3))) unsigned int*)(l), 16, 0, 0)

__global__ __launch_bounds__(512, 2) void gemm_bt(
    const u16* __restrict__ A, const u16* __restrict__ B,
    float* __restrict__ C, const u32* __restrict__ amax_bits, int bm_base)
{
    // [buf][mat A=0/B=1][half][128 rows * 64 cols] bf16, 16 KiB per half
    __shared__ u16 sh[2][2][2][8192];

    const int tid = threadIdx.x;
    const int w = tid >> 6, lane = tid & 63;

    // XCD swizzle (256 blocks/dispatch, 256%8==0 -> bijective):
    // each XCD owns 4 bm rows x 8 bn.
    const int id = blockIdx.x;
    const int xcd = id & 7;
    const int local = id >> 3;                   // 0..31 per XCD
    const int bm = bm_base + xcd * 4 + (local >> 3);   // 32 bm per dispatch
    const int bn = local & 7;                    // 0..7   (N/256)

    const int wm = w >> 2, wn = w & 3;           // 2x4 wave grid
    const int r16 = lane & 15, q = lane >> 4;

    floatx4 acc[8][4] = {};

    // ---- swizzled fragment read offsets (u16 units) ----
    const int swz = (r16 & 7) << 4;                          // byte XOR value
    const int aoff0 = r16 * 64 + (((q * 16) ^ swz) >> 1);          // ks=0
    const int aoff1 = r16 * 64 + (((64 + q * 16) ^ swz) >> 1);     // ks=1

    // ---- staging source pointers (pre-swizzled per lane) ----
    const int srow8 = lane >> 3;                             // 0..7
    const int scol = ((lane & 7) ^ srow8) * 8;               // u16 units
    const u16* gA[2], * gB[2];
    gA[0] = A + (size_t)(bm * 256 + (w * 2 + 0) * 8 + srow8) * K + scol;
    gA[1] = A + (size_t)(bm * 256 + (w * 2 + 1) * 8 + srow8) * K + scol;
    gB[0] = B + (size_t)(bn * 256 + (w * 2 + 0) * 8 + srow8) * K + scol;
    gB[1] = B + (size_t)(bn * 256 + (w * 2 + 1) * 8 + srow8) * K + scol;

#define STG(buf, mat, half, ktc) do {                                           \
        const u16* _s0 = ((mat) ? gB[0] : gA[0]) + (size_t)(half) * 128 * K + (ktc); \
        const u16* _s1 = ((mat) ? gB[1] : gA[1]) + (size_t)(half) * 128 * K + (ktc); \
        GLDS(_s0, &sh[buf][mat][half][w * 1024]);                               \
        GLDS(_s1, &sh[buf][mat][half][w * 1024 + 512]);                         \
    } while (0)

    short8 aF[4][2], bF[4][2];

#define RD_A(buf, Qa) do {                                                      \
        const u16* _ar = &sh[buf][0][wm][(Qa) * 4096];                          \
        _Pragma("unroll") for (int _i = 0; _i < 4; _i++) {                      \
            aF[_i][0] = *(const short8*)(_ar + _i * 1024 + aoff0);              \
            aF[_i][1] = *(const short8*)(_ar + _i * 1024 + aoff1); }            \
    } while (0)

#define RD_B(buf, Qb) do {                                                      \
        const u16* _br = &sh[buf][1][wn >> 1][(wn & 1) * 4096 + (Qb) * 2048];   \
        _Pragma("unroll") for (int _j = 0; _j < 2; _j++) {                      \
            bF[(Qb) * 2 + _j][0] = *(const short8*)(_br + _j * 1024 + aoff0);   \
            bF[(Qb) * 2 + _j][1] = *(const short8*)(_br + _j * 1024 + aoff1); } \
    } while (0)

    // 16 MFMAs of one quadrant; registers only, no sync
#define MMAQ(Qa, Qb)                                                            \
        _Pragma("unroll") for (int _i = 0; _i < 4; _i++)                        \
        _Pragma("unroll") for (int _j = 0; _j < 2; _j++)                        \
        _Pragma("unroll") for (int _k = 0; _k < 2; _k++)                        \
            acc[(Qa) * 4 + _i][(Qb) * 2 + _j] =                                 \
                __builtin_amdgcn_mfma_f32_16x16x32_bf16(                        \
                    aF[_i][_k], bF[(Qb) * 2 + _j][_k],                          \
                    acc[(Qa) * 4 + _i][(Qb) * 2 + _j], 0, 0, 0)

#define BAR do { __builtin_amdgcn_sched_barrier(0);                             \
                 __builtin_amdgcn_s_barrier();                                  \
                 __builtin_amdgcn_sched_barrier(0); } while (0)
#define PRIO1 __builtin_amdgcn_s_setprio(1)
#define PRIO0 do { __builtin_amdgcn_s_setprio(0);                               \
                   __builtin_amdgcn_sched_barrier(0); } while (0)
#define ENDPH do { __builtin_amdgcn_s_barrier();                                \
                   __builtin_amdgcn_sched_barrier(0); } while (0)
#define CHK4 do { asm volatile("s_waitcnt vmcnt(4)" ::: "memory");              \
                  __builtin_amdgcn_sched_barrier(0); } while (0)

    // ---- prologue: X(kt0) fully + Y(kt1) B halves ----
    STG(0, 0, 0, 0); STG(0, 0, 1, 0);        // X.A0 X.A1
    STG(0, 1, 0, 0); STG(0, 1, 1, 0);        // X.B0 X.B1
    STG(1, 1, 0, 64); STG(1, 1, 1, 64);      // Y.B0 Y.B1
    CHK4;                                     // X landed; Y.B may fly
    __builtin_amdgcn_s_barrier();

#pragma unroll 1
    for (int it = 0; it < K / 128; ++it) {
        const int ktY  = (2 * it + 1) * 64;
        const int kx2  = 2 * it + 2, ky2 = 2 * it + 3;
        const int ktX2 = (kx2 <= 31 ? kx2 : 31) * 64;   // clamp: last-iter
        const int ktY2 = (ky2 <= 31 ? ky2 : 31) * 64;   // stages are dummies

        // ---- X tile (buf 0) ----
        // P1
        RD_A(0, 0); RD_B(0, 0); STG(1, 0, 0, ktY);
        BAR; PRIO1; MMAQ(0, 0); PRIO0; ENDPH;
        // P2
        RD_B(0, 1); STG(1, 0, 1, ktY);
        BAR; PRIO1; MMAQ(0, 1); PRIO0; ENDPH;
        // P34 (merged)
        RD_A(0, 1); STG(0, 1, 0, ktX2); STG(0, 1, 1, ktX2);
        BAR; PRIO1; MMAQ(1, 1); MMAQ(1, 0); PRIO0; CHK4; ENDPH;
        // ---- Y tile (buf 1) ----
        // P5
        RD_A(1, 0); RD_B(1, 0); STG(0, 0, 0, ktX2);
        BAR; PRIO1; MMAQ(0, 0); PRIO0; ENDPH;
        // P6
        RD_B(1, 1); STG(0, 0, 1, ktX2);
        BAR; PRIO1; MMAQ(0, 1); PRIO0; ENDPH;
        // P78 (merged)
        RD_A(1, 1); STG(1, 1, 0, ktY2); STG(1, 1, 1, ktY2);
        BAR; PRIO1; MMAQ(1, 1); MMAQ(1, 0); PRIO0; CHK4; ENDPH;
    }

    // drain stray (clamped) stages before LDS dealloc / epilogue
    asm volatile("s_waitcnt vmcnt(0)" ::: "memory");

    float pts = pts_from_amax(__uint_as_float(*amax_bits));

    // C/D layout (verified m89/m91): col = lane&15, row = (lane>>4)*4 + reg
    float* Cb = C + (size_t)(bm * 256 + wm * 128 + q * 4) * N
                  + bn * 256 + wn * 64 + r16;
#pragma unroll
    for (int i = 0; i < 8; i++)
#pragma unroll
        for (int j = 0; j < 4; j++)
#pragma unroll
            for (int t = 0; t < 4; t++)
                Cb[(size_t)(i * 16 + t) * N + j * 16] = pts * acc[i][j][t];
}

// ---- launch --------------------------------------------------------------

extern "C" void kernel_launch(void* const* d_in, const int* in_sizes, int n_in,
                              void* d_out, int out_size, void* d_ws, size_t ws_size,
                              hipStream_t stream) {
    const float* x   = (const float*)d_in[0];
    const int*   wp  = (const int*)d_in[1];
    const float* wsc = (const float*)d_in[2];
    const float* wgs = (const float*)d_in[3];
    float* out = (float*)d_out;

    u32*   amax_ws = (u32*)d_ws;
    float* part    = (float*)((char*)d_ws + 64);
    u16*   aq      = (u16*)((char*)d_ws + 16384);
    u16*   wq      = aq + (size_t)M * K;

    amax_part<<<2048, 256, 0, stream>>>((const float4*)x, part, M * K / 4,
                                        wp, wsc, wgs, wq);
    amax_fin<<<1, 1024, 0, stream>>>(part, amax_ws);
    prep<<<QB, 256, 0, stream>>>((const float4*)x, (uint2*)aq, amax_ws);
    gemm_bt<<<256, 512, 0, stream>>>(aq, wq, out, amax_ws, 0);
    gemm_bt<<<256, 512, 0, stream>>>(aq, wq, out, amax_ws, 32);
}